// Round 2
// baseline (13913.535 us; speedup 1.0000x reference)
//
#include <hip/hip_runtime.h>
#include <math.h>

#define B_   512
#define T_   200
#define D_   256
#define H_   256
#define ROWS 2
#define NBLK (B_ / ROWS)   // 256 blocks, 1 per CU
#define NTH  512

typedef _Float16 h2v __attribute__((ext_vector_type(2)));
typedef _Float16 h8v __attribute__((ext_vector_type(8)));
union H8 { h8v v; h2v p[4]; };

#if __has_builtin(__builtin_amdgcn_fdot2)
#define FDOT2(a, b, c) __builtin_amdgcn_fdot2((a), (b), (c), false)
#else
#define FDOT2(a, b, c) fmaf((float)(a).x, (float)(b).x, fmaf((float)(a).y, (float)(b).y, (c)))
#endif

__device__ __forceinline__ float sigmoid_f(float x) {
    return 1.0f / (1.0f + __expf(-x));
}
__device__ __forceinline__ float tanh_f(float x) {
    return 1.0f - 2.0f / (__expf(2.0f * x) + 1.0f);
}

// ---- weight conversion: fp32 -> packed f16x2 along K ----
// wg2[kp*512 + c] = (gk[2kp][c], gk[2kp+1][c])   kp in [0,256), c in [0,512)
// wc2[kp*256 + c] = (ck[2kp][c], ck[2kp+1][c])   kp in [0,256), c in [0,256)
__global__ void conv_weights(const float* __restrict__ gk,
                             const float* __restrict__ ck,
                             h2v* __restrict__ wg2, h2v* __restrict__ wc2) {
    int i = blockIdx.x * 256 + threadIdx.x;
    const int NG = 256 * 512;
    if (i < NG) {
        int kp = i >> 9, c = i & 511;
        h2v w;
        w.x = (_Float16)gk[(2 * kp) * 512 + c];
        w.y = (_Float16)gk[(2 * kp + 1) * 512 + c];
        wg2[i] = w;
    } else {
        int j = i - NG;
        if (j < 256 * 256) {
            int kp = j >> 8, c = j & 255;
            h2v w;
            w.x = (_Float16)ck[(2 * kp) * 256 + c];
            w.y = (_Float16)ck[(2 * kp + 1) * 256 + c];
            wc2[j] = w;
        }
    }
}

__global__ __launch_bounds__(NTH) void gru_persist(
    const float* __restrict__ x,    // [B, T, D] fp32
    const int*   __restrict__ slen, // [B, 1]
    const h2v*   __restrict__ wg2,  // packed gate weights [256 kp][512 c]
    const float* __restrict__ gb,   // [512]
    const h2v*   __restrict__ wc2,  // packed cand weights [256 kp][256 c]
    const float* __restrict__ cb,   // [256]
    float* __restrict__ out)        // [B, T, H] fp32
{
    // [x | h] concat as f16, packed-pair friendly (256 even, no straddle)
    __shared__ __align__(16) _Float16 xh_h[ROWS][512];
    __shared__ __align__(16) _Float16 rh_h[ROWS][256];  // r*h for candidate
    __shared__ float uls[ROWS][256];                     // update gate

    const int tid = threadIdx.x;
    const int b0  = blockIdx.x * ROWS;
    const int c   = tid;          // gate column 0..511
    const int cc  = tid & 255;    // col 0..255
    const int row = tid >> 8;     // 0..1

    // init h = 0
    xh_h[row][256 + cc] = (_Float16)0.0f;

    const int   len0  = slen[b0];
    const int   len1  = slen[b0 + 1];
    const float gbias = gb[c];
    const float cbias = cb[cc];

    const h2v* wg = wg2 + c;   // stride 512 per kp
    const h2v* wc = wc2 + cc;  // stride 256 per kp

    for (int t = 0; t < T_; ++t) {
        __syncthreads();  // h writes of prev step done
        // ---- stage x_t (fp32 -> f16) ----
        xh_h[row][cc] = (_Float16)x[((size_t)(b0 + row) * T_ + t) * D_ + cc];
        __syncthreads();

        // ---- gates: thread owns column c for BOTH rows (zero redundancy) ----
        float a0e = 0.f, a0o = 0.f, a1e = 0.f, a1o = 0.f;
        {
            const h8v* v0 = (const h8v*)&xh_h[0][0];
            const h8v* v1 = (const h8v*)&xh_h[1][0];
            for (int q = 0; q < 64; ++q) {
                H8 x0, x1;
                x0.v = v0[q];
                x1.v = v1[q];
                h2v w0 = wg[(size_t)(4 * q + 0) * 512];
                h2v w1 = wg[(size_t)(4 * q + 1) * 512];
                h2v w2 = wg[(size_t)(4 * q + 2) * 512];
                h2v w3 = wg[(size_t)(4 * q + 3) * 512];
                a0e = FDOT2(x0.p[0], w0, a0e); a0o = FDOT2(x0.p[1], w1, a0o);
                a0e = FDOT2(x0.p[2], w2, a0e); a0o = FDOT2(x0.p[3], w3, a0o);
                a1e = FDOT2(x1.p[0], w0, a1e); a1o = FDOT2(x1.p[1], w1, a1o);
                a1e = FDOT2(x1.p[2], w2, a1e); a1o = FDOT2(x1.p[3], w3, a1o);
            }
        }
        float g0 = sigmoid_f(a0e + a0o + gbias);
        float g1 = sigmoid_f(a1e + a1o + gbias);
        if (c < 256) {  // reset gate -> stage r*h
            rh_h[0][c] = (_Float16)(g0 * (float)xh_h[0][256 + c]);
            rh_h[1][c] = (_Float16)(g1 * (float)xh_h[1][256 + c]);
        } else {        // update gate
            uls[0][c - 256] = g0;
            uls[1][c - 256] = g1;
        }
        __syncthreads();

        // ---- candidate + h update: threads 0..255, column cc, both rows ----
        if (tid < 256) {
            float b0e = 0.f, b0o = 0.f, b1e = 0.f, b1o = 0.f;
            const h8v* v0 = (const h8v*)&xh_h[0][0];   // x part: halves 0..255
            const h8v* v1 = (const h8v*)&xh_h[1][0];
            for (int q = 0; q < 32; ++q) {
                H8 x0, x1;
                x0.v = v0[q];
                x1.v = v1[q];
                h2v w0 = wc[(size_t)(4 * q + 0) * 256];
                h2v w1 = wc[(size_t)(4 * q + 1) * 256];
                h2v w2 = wc[(size_t)(4 * q + 2) * 256];
                h2v w3 = wc[(size_t)(4 * q + 3) * 256];
                b0e = FDOT2(x0.p[0], w0, b0e); b0o = FDOT2(x0.p[1], w1, b0o);
                b0e = FDOT2(x0.p[2], w2, b0e); b0o = FDOT2(x0.p[3], w3, b0o);
                b1e = FDOT2(x1.p[0], w0, b1e); b1o = FDOT2(x1.p[1], w1, b1o);
                b1e = FDOT2(x1.p[2], w2, b1e); b1o = FDOT2(x1.p[3], w3, b1o);
            }
            const h8v* r0 = (const h8v*)&rh_h[0][0];   // r*h part
            const h8v* r1 = (const h8v*)&rh_h[1][0];
            for (int q = 0; q < 32; ++q) {
                H8 x0, x1;
                x0.v = r0[q];
                x1.v = r1[q];
                h2v w0 = wc[(size_t)(128 + 4 * q + 0) * 256];
                h2v w1 = wc[(size_t)(128 + 4 * q + 1) * 256];
                h2v w2 = wc[(size_t)(128 + 4 * q + 2) * 256];
                h2v w3 = wc[(size_t)(128 + 4 * q + 3) * 256];
                b0e = FDOT2(x0.p[0], w0, b0e); b0o = FDOT2(x0.p[1], w1, b0o);
                b0e = FDOT2(x0.p[2], w2, b0e); b0o = FDOT2(x0.p[3], w3, b0o);
                b1e = FDOT2(x1.p[0], w0, b1e); b1o = FDOT2(x1.p[1], w1, b1o);
                b1e = FDOT2(x1.p[2], w2, b1e); b1o = FDOT2(x1.p[3], w3, b1o);
            }
            float c0 = tanh_f(b0e + b0o + cbias);
            float c1 = tanh_f(b1e + b1o + cbias);

            float h0 = (float)xh_h[0][256 + cc];
            float h1 = (float)xh_h[1][256 + cc];
            float u0 = uls[0][cc];
            float u1 = uls[1][cc];
            float n0 = u0 * h0 + (1.0f - u0) * c0;
            float n1 = u1 * h1 + (1.0f - u1) * c1;
            bool  v0ok = (t < len0);
            bool  v1ok = (t < len1);

            out[((size_t)(b0 + 0) * T_ + t) * H_ + cc] = v0ok ? n0 : 0.0f;
            out[((size_t)(b0 + 1) * T_ + t) * H_ + cc] = v1ok ? n1 : 0.0f;
            if (v0ok) xh_h[0][256 + cc] = (_Float16)n0;
            if (v1ok) xh_h[1][256 + cc] = (_Float16)n1;
        }
    }
}

extern "C" void kernel_launch(void* const* d_in, const int* in_sizes, int n_in,
                              void* d_out, int out_size, void* d_ws, size_t ws_size,
                              hipStream_t stream) {
    const float* x    = (const float*)d_in[0];
    const int*   slen = (const int*)  d_in[1];
    const float* gk   = (const float*)d_in[2];
    const float* gb   = (const float*)d_in[3];
    const float* ck   = (const float*)d_in[4];
    const float* cb   = (const float*)d_in[5];
    float* out = (float*)d_out;

    h2v* wg2 = (h2v*)d_ws;                       // 256*512*4B = 512 KB
    h2v* wc2 = (h2v*)((char*)d_ws + 512 * 1024); // 256*256*4B = 256 KB

    // pack weights to f16x2 (768 KB of ws)
    conv_weights<<<768, 256, 0, stream>>>(gk, ck, wg2, wc2);
    // persistent recurrent kernel: 256 blocks (1/CU), 512 threads
    gru_persist<<<NBLK, NTH, 0, stream>>>(x, slen, wg2, gb, wc2, cb, out);
}

// Round 3
// 4825.086 us; speedup vs baseline: 2.8836x; 2.8836x over previous
//
#include <hip/hip_runtime.h>
#include <math.h>

#define B_ 512
#define T_ 200
#define D_ 256
#define H_ 256

typedef unsigned int  u32;
typedef unsigned short u16;

__device__ __forceinline__ float sigmoid_f(float x) { return 1.0f / (1.0f + __expf(-x)); }
__device__ __forceinline__ float tanh_f(float x)    { return 1.0f - 2.0f / (__expf(2.0f * x) + 1.0f); }

__device__ __forceinline__ u32 pack2h(float a, float b) {
    union { _Float16 h[2]; u32 u; } r;
    r.h[0] = (_Float16)a; r.h[1] = (_Float16)b; return r.u;
}
__device__ __forceinline__ float unpLo(u32 u) { union { u32 u; _Float16 h[2]; } r; r.u = u; return (float)r.h[0]; }
__device__ __forceinline__ float unpHi(u32 u) { union { u32 u; _Float16 h[2]; } r; r.u = u; return (float)r.h[1]; }

__device__ __forceinline__ float sel4(float a0, float a1, float a2, float a3, int i) {
    float x01 = (i & 1) ? a1 : a0;
    float x23 = (i & 1) ? a3 : a2;
    return (i & 2) ? x23 : x01;
}

// ============================================================================
// Projection GEMM: proj = x @ W_x (+bias), for all (b,t).
//   gy 0..3: gate cols (gk rows 0..255), f16 pairs packed into d_out (u32 view)
//   gy 4..5: cand cols (ck rows 0..255), f16 into ws
// grid (1600, 6|4), block 256. Tile: 64 rows x 128 cols, K staged 2x128 in LDS.
// ============================================================================
__global__ __launch_bounds__(256) void proj_x(
    const float* __restrict__ x,  const float* __restrict__ gk,
    const float* __restrict__ gb, const float* __restrict__ ck,
    const float* __restrict__ cb,
    u32* pg,                      // aliases d_out: [102400][256] u32 (512 f16)
    u16* __restrict__ pc)         // ws: [102400][256] f16
{
    __shared__ float xs[64][128];
    const int  tid  = threadIdx.x;
    const int  m0   = blockIdx.x * 64;
    const int  gy   = blockIdx.y;
    const bool isG  = (gy < 4);
    const int  nc   = isG ? 512 : 256;
    const int  c4   = (isG ? gy * 128 : (gy - 4) * 128) + 4 * (tid & 31);
    const int  rg   = tid >> 5;                  // 0..7 -> rows rg*8..rg*8+7
    const float* W  = isG ? gk : ck;

    float acc[8][4] = {};

    for (int ks = 0; ks < 256; ks += 128) {
        __syncthreads();
        // stage x tile [64][128]
        #pragma unroll
        for (int q = 0; q < 8; ++q) {
            int f = tid + 256 * q;               // 0..2047
            int r = f >> 5, cq = f & 31;
            *(float4*)&xs[r][4 * cq] =
                *(const float4*)&x[(size_t)(m0 + r) * 256 + ks + 4 * cq];
        }
        __syncthreads();
        for (int kk = 0; kk < 128; kk += 4) {
            float4 w0 = *(const float4*)&W[(size_t)(ks + kk + 0) * nc + c4];
            float4 w1 = *(const float4*)&W[(size_t)(ks + kk + 1) * nc + c4];
            float4 w2 = *(const float4*)&W[(size_t)(ks + kk + 2) * nc + c4];
            float4 w3 = *(const float4*)&W[(size_t)(ks + kk + 3) * nc + c4];
            #pragma unroll
            for (int i = 0; i < 8; ++i) {
                float4 xv = *(const float4*)&xs[rg * 8 + i][kk];
                acc[i][0] = fmaf(xv.x, w0.x, acc[i][0]); acc[i][0] = fmaf(xv.y, w1.x, acc[i][0]);
                acc[i][0] = fmaf(xv.z, w2.x, acc[i][0]); acc[i][0] = fmaf(xv.w, w3.x, acc[i][0]);
                acc[i][1] = fmaf(xv.x, w0.y, acc[i][1]); acc[i][1] = fmaf(xv.y, w1.y, acc[i][1]);
                acc[i][1] = fmaf(xv.z, w2.y, acc[i][1]); acc[i][1] = fmaf(xv.w, w3.y, acc[i][1]);
                acc[i][2] = fmaf(xv.x, w0.z, acc[i][2]); acc[i][2] = fmaf(xv.y, w1.z, acc[i][2]);
                acc[i][2] = fmaf(xv.z, w2.z, acc[i][2]); acc[i][2] = fmaf(xv.w, w3.z, acc[i][2]);
                acc[i][3] = fmaf(xv.x, w0.w, acc[i][3]); acc[i][3] = fmaf(xv.y, w1.w, acc[i][3]);
                acc[i][3] = fmaf(xv.z, w2.w, acc[i][3]); acc[i][3] = fmaf(xv.w, w3.w, acc[i][3]);
            }
        }
    }

    if (isG) {
        float b0v = gb[c4], b1v = gb[c4 + 1], b2v = gb[c4 + 2], b3v = gb[c4 + 3];
        #pragma unroll
        for (int i = 0; i < 8; ++i) {
            int m = m0 + rg * 8 + i;
            uint2 v;
            v.x = pack2h(acc[i][0] + b0v, acc[i][1] + b1v);
            v.y = pack2h(acc[i][2] + b2v, acc[i][3] + b3v);
            *(uint2*)&pg[(size_t)m * 256 + (c4 >> 1)] = v;
        }
    } else {
        float b0v = cb[c4], b1v = cb[c4 + 1], b2v = cb[c4 + 2], b3v = cb[c4 + 3];
        #pragma unroll
        for (int i = 0; i < 8; ++i) {
            int m = m0 + rg * 8 + i;
            uint2 v;
            v.x = pack2h(acc[i][0] + b0v, acc[i][1] + b1v);
            v.y = pack2h(acc[i][2] + b2v, acc[i][3] + b3v);
            *(uint2*)&pc[(size_t)m * 256 + c4] = v;
        }
    }
}

// ============================================================================
// Recurrent kernel. 128 blocks x 1024 threads, 4 batch rows per block.
// Gates:  K=256 (h part),   lanes: sg=tid&7 K-split, cgp=tid>>3 col quad.
// Cand:   K=256 (r*h part) [WSP] or K=512 inline [!WSP],
//         lanes: sc=tid&15 K-split, cgc=tid>>4 col quad.
// Shuffle-butterfly K reduction; 2 __syncthreads per step; 16 KB LDS.
// ============================================================================
template <bool WSP>
__global__ __launch_bounds__(1024) void gru_rec(
    const int*   __restrict__ slen,
    const float* __restrict__ gk, const float* __restrict__ ck,
    const float* __restrict__ cb, const float* __restrict__ x,
    const u32* pg,                 // aliases d_out (gate x-proj, f16)
    const u16* __restrict__ pc,    // ws (cand x-proj, f16), WSP only
    float* out)                    // aliases pg!
{
    __shared__ float hs[4][256];
    __shared__ float rh[4][256];
    __shared__ float uu[4][256];
    __shared__ float xs[4][256];   // !WSP only

    const int tid = threadIdx.x;
    const int b0  = blockIdx.x * 4;

    const int sg  = tid & 7,  cgp = tid >> 3;       // gate mapping
    const int gro = sg & 3;
    const int gc0 = 4 * cgp + ((sg >> 2) << 1);     // owned col pair
    const int sc  = tid & 15, cgc = tid >> 4;       // cand mapping
    const int cro = sc & 3;
    const int cco = 4 * cgc + (sc >> 2);            // owned col

    hs[tid >> 8][tid & 255] = 0.0f;

    const int len0 = slen[b0], len1 = slen[b0 + 1], len2 = slen[b0 + 2], len3 = slen[b0 + 3];
    const int lenC = (cro == 0) ? len0 : (cro == 1) ? len1 : (cro == 2) ? len2 : len3;

    const float* wgh = gk + 256 * 512 + 4 * cgp;                 // h-part rows
    const float* wch = ck + (WSP ? 256 * 256 : 0) + 4 * cgc;
    const u32*   pgp = pg + (size_t)(b0 + gro) * T_ * 256 + (gc0 >> 1);
    const u16*   pcp = pc + (size_t)(b0 + cro) * T_ * 256 + cco;
    const float  cbias = WSP ? 0.0f : cb[cco];
    float*       outp  = out + (size_t)(b0 + cro) * T_ * 256 + cco;
    const float* xrow  = x + (size_t)(b0 + (tid >> 8)) * T_ * 256 + (tid & 255);

    for (int t = 0; t < T_; ++t) {
        // prefetch this step's projections (register-only; barrier-ordered
        // ahead of this step's out-write into the same d_out slots)
        const u32  pgv = pgp[(size_t)t * 256];
        float pcv = 0.0f;
        if (WSP) pcv = (float)*(const _Float16*)&pcp[(size_t)t * 256];

        __syncthreads();                      // A: hs(t-1) complete
        if (!WSP) xs[tid >> 8][tid & 255] = xrow[(size_t)t * 256];

        // ---------------- gates: h @ Wg_h ----------------
        float ag[4][4] = {};
        #pragma unroll
        for (int j = 0; j < 8; ++j) {
            const int k0 = 4 * sg + 32 * j;
            float h0[4], h1[4], h2[4], h3[4];
            *(float4*)h0 = *(const float4*)&hs[0][k0];
            *(float4*)h1 = *(const float4*)&hs[1][k0];
            *(float4*)h2 = *(const float4*)&hs[2][k0];
            *(float4*)h3 = *(const float4*)&hs[3][k0];
            #pragma unroll
            for (int kk = 0; kk < 4; ++kk) {
                float4 w = *(const float4*)&wgh[(size_t)(k0 + kk) * 512];
                ag[0][0] = fmaf(h0[kk], w.x, ag[0][0]); ag[0][1] = fmaf(h0[kk], w.y, ag[0][1]);
                ag[0][2] = fmaf(h0[kk], w.z, ag[0][2]); ag[0][3] = fmaf(h0[kk], w.w, ag[0][3]);
                ag[1][0] = fmaf(h1[kk], w.x, ag[1][0]); ag[1][1] = fmaf(h1[kk], w.y, ag[1][1]);
                ag[1][2] = fmaf(h1[kk], w.z, ag[1][2]); ag[1][3] = fmaf(h1[kk], w.w, ag[1][3]);
                ag[2][0] = fmaf(h2[kk], w.x, ag[2][0]); ag[2][1] = fmaf(h2[kk], w.y, ag[2][1]);
                ag[2][2] = fmaf(h2[kk], w.z, ag[2][2]); ag[2][3] = fmaf(h2[kk], w.w, ag[2][3]);
                ag[3][0] = fmaf(h3[kk], w.x, ag[3][0]); ag[3][1] = fmaf(h3[kk], w.y, ag[3][1]);
                ag[3][2] = fmaf(h3[kk], w.z, ag[3][2]); ag[3][3] = fmaf(h3[kk], w.w, ag[3][3]);
            }
        }
        #pragma unroll
        for (int m = 1; m < 8; m <<= 1)
            #pragma unroll
            for (int r = 0; r < 4; ++r)
                #pragma unroll
                for (int ci = 0; ci < 4; ++ci)
                    ag[r][ci] += __shfl_xor(ag[r][ci], m, 64);
        {
            const int hi = sg >> 2;
            float r0 = sel4(ag[0][0], ag[1][0], ag[2][0], ag[3][0], gro);
            float r1 = sel4(ag[0][1], ag[1][1], ag[2][1], ag[3][1], gro);
            float r2 = sel4(ag[0][2], ag[1][2], ag[2][2], ag[3][2], gro);
            float r3 = sel4(ag[0][3], ag[1][3], ag[2][3], ag[3][3], gro);
            float v0 = hi ? r2 : r0;
            float v1 = hi ? r3 : r1;
            float g0 = sigmoid_f(v0 + unpLo(pgv));
            float g1 = sigmoid_f(v1 + unpHi(pgv));
            if (gc0 < 256) {
                rh[gro][gc0]     = g0 * hs[gro][gc0];
                rh[gro][gc0 + 1] = g1 * hs[gro][gc0 + 1];
            } else {
                uu[gro][gc0 - 256]     = g0;
                uu[gro][gc0 + 1 - 256] = g1;
            }
        }
        __syncthreads();                      // B: rh/uu (and xs) ready

        // ---------------- candidate ----------------
        float ac[4][4] = {};
        const int JC = WSP ? 4 : 8;
        #pragma unroll
        for (int j = 0; j < JC; ++j) {
            const int k0 = 4 * sc + 64 * j;
            const float (*src)[256] = (!WSP && j < 4) ? xs : rh;
            const int ks = (!WSP && j >= 4) ? (k0 - 256) : ((!WSP) ? k0 : k0);
            float h0[4], h1[4], h2[4], h3[4];
            *(float4*)h0 = *(const float4*)&src[0][ks];
            *(float4*)h1 = *(const float4*)&src[1][ks];
            *(float4*)h2 = *(const float4*)&src[2][ks];
            *(float4*)h3 = *(const float4*)&src[3][ks];
            #pragma unroll
            for (int kk = 0; kk < 4; ++kk) {
                float4 w = *(const float4*)&wch[(size_t)(k0 + kk) * 256];
                ac[0][0] = fmaf(h0[kk], w.x, ac[0][0]); ac[0][1] = fmaf(h0[kk], w.y, ac[0][1]);
                ac[0][2] = fmaf(h0[kk], w.z, ac[0][2]); ac[0][3] = fmaf(h0[kk], w.w, ac[0][3]);
                ac[1][0] = fmaf(h1[kk], w.x, ac[1][0]); ac[1][1] = fmaf(h1[kk], w.y, ac[1][1]);
                ac[1][2] = fmaf(h1[kk], w.z, ac[1][2]); ac[1][3] = fmaf(h1[kk], w.w, ac[1][3]);
                ac[2][0] = fmaf(h2[kk], w.x, ac[2][0]); ac[2][1] = fmaf(h2[kk], w.y, ac[2][1]);
                ac[2][2] = fmaf(h2[kk], w.z, ac[2][2]); ac[2][3] = fmaf(h2[kk], w.w, ac[2][3]);
                ac[3][0] = fmaf(h3[kk], w.x, ac[3][0]); ac[3][1] = fmaf(h3[kk], w.y, ac[3][1]);
                ac[3][2] = fmaf(h3[kk], w.z, ac[3][2]); ac[3][3] = fmaf(h3[kk], w.w, ac[3][3]);
            }
        }
        #pragma unroll
        for (int m = 1; m < 16; m <<= 1)
            #pragma unroll
            for (int r = 0; r < 4; ++r)
                #pragma unroll
                for (int ci = 0; ci < 4; ++ci)
                    ac[r][ci] += __shfl_xor(ac[r][ci], m, 64);
        {
            float r0 = sel4(ac[0][0], ac[1][0], ac[2][0], ac[3][0], cro);
            float r1 = sel4(ac[0][1], ac[1][1], ac[2][1], ac[3][1], cro);
            float r2 = sel4(ac[0][2], ac[1][2], ac[2][2], ac[3][2], cro);
            float r3 = sel4(ac[0][3], ac[1][3], ac[2][3], ac[3][3], cro);
            float sum = sel4(r0, r1, r2, r3, sc >> 2);
            float cd  = tanh_f(sum + (WSP ? pcv : cbias));
            float u    = uu[cro][cco];
            float hold = hs[cro][cco];
            float hn   = u * hold + (1.0f - u) * cd;
            bool  valid = (t < lenC);
            outp[(size_t)t * 256] = valid ? hn : 0.0f;
            if (valid) hs[cro][cco] = hn;
        }
    }
}

extern "C" void kernel_launch(void* const* d_in, const int* in_sizes, int n_in,
                              void* d_out, int out_size, void* d_ws, size_t ws_size,
                              hipStream_t stream) {
    const float* x    = (const float*)d_in[0];
    const int*   slen = (const int*)  d_in[1];
    const float* gk   = (const float*)d_in[2];
    const float* gb   = (const float*)d_in[3];
    const float* ck   = (const float*)d_in[4];
    const float* cb   = (const float*)d_in[5];
    float* out = (float*)d_out;
    u32*   pg  = (u32*)d_out;
    u16*   pc  = (u16*)d_ws;

    const bool wsp = ws_size >= (size_t)B_ * T_ * 256 * sizeof(u16);  // 52.4 MB

    dim3 pgrid(1600, wsp ? 6 : 4);
    proj_x<<<pgrid, 256, 0, stream>>>(x, gk, gb, ck, cb, pg, pc);

    if (wsp) gru_rec<true ><<<128, 1024, 0, stream>>>(slen, gk, ck, cb, x, pg, pc, out);
    else     gru_rec<false><<<128, 1024, 0, stream>>>(slen, gk, ck, cb, x, pg, pc, out);
}

// Round 4
// 1265.675 us; speedup vs baseline: 10.9930x; 3.8123x over previous
//
#include <hip/hip_runtime.h>
#include <math.h>

#define B_ 512
#define T_ 200
#define D_ 256
#define H_ 256

typedef unsigned int   u32;
typedef unsigned short u16;
typedef _Float16 h2 __attribute__((ext_vector_type(2)));
union U4H { uint4 u; h2 p[4]; };

__device__ __forceinline__ float sigmoid_f(float x) { return 1.0f / (1.0f + __expf(-x)); }
__device__ __forceinline__ float tanh_f(float x)    { return 1.0f - 2.0f / (__expf(2.0f * x) + 1.0f); }

#if __has_builtin(__builtin_amdgcn_fdot2)
#define FDOT2(a, b, c) __builtin_amdgcn_fdot2((a), (b), (c), false)
#else
#define FDOT2(a, b, c) fmaf((float)(a).x, (float)(b).x, fmaf((float)(a).y, (float)(b).y, (c)))
#endif

__device__ __forceinline__ u32 pack2h(float a, float b) {
    union { h2 h; u32 u; } r;
    r.h.x = (_Float16)a; r.h.y = (_Float16)b; return r.u;
}
__device__ __forceinline__ float unp(u32 u, int hi) {
    union { u32 u; _Float16 h[2]; } r; r.u = u; return (float)r.h[hi];
}

// ============================================================================
// Projection GEMM (unchanged from R3): proj = x @ W_x (+bias), all (b,t).
//   gy 0..3: gate cols -> f16 pairs packed into d_out (u32 view)
//   gy 4..5: cand cols -> f16 into ws
// ============================================================================
__global__ __launch_bounds__(256) void proj_x(
    const float* __restrict__ x,  const float* __restrict__ gk,
    const float* __restrict__ gb, const float* __restrict__ ck,
    const float* __restrict__ cb,
    u32* pg,                      // aliases d_out: [102400][256] u32 (512 f16)
    u16* __restrict__ pc)         // ws: [102400][256] f16
{
    __shared__ float xs[64][128];
    const int  tid  = threadIdx.x;
    const int  m0   = blockIdx.x * 64;
    const int  gy   = blockIdx.y;
    const bool isG  = (gy < 4);
    const int  nc   = isG ? 512 : 256;
    const int  c4   = (isG ? gy * 128 : (gy - 4) * 128) + 4 * (tid & 31);
    const int  rg   = tid >> 5;
    const float* W  = isG ? gk : ck;

    float acc[8][4] = {};

    for (int ks = 0; ks < 256; ks += 128) {
        __syncthreads();
        #pragma unroll
        for (int q = 0; q < 8; ++q) {
            int f = tid + 256 * q;
            int r = f >> 5, cq = f & 31;
            *(float4*)&xs[r][4 * cq] =
                *(const float4*)&x[(size_t)(m0 + r) * 256 + ks + 4 * cq];
        }
        __syncthreads();
        for (int kk = 0; kk < 128; kk += 4) {
            float4 w0 = *(const float4*)&W[(size_t)(ks + kk + 0) * nc + c4];
            float4 w1 = *(const float4*)&W[(size_t)(ks + kk + 1) * nc + c4];
            float4 w2 = *(const float4*)&W[(size_t)(ks + kk + 2) * nc + c4];
            float4 w3 = *(const float4*)&W[(size_t)(ks + kk + 3) * nc + c4];
            #pragma unroll
            for (int i = 0; i < 8; ++i) {
                float4 xv = *(const float4*)&xs[rg * 8 + i][kk];
                acc[i][0] = fmaf(xv.x, w0.x, acc[i][0]); acc[i][0] = fmaf(xv.y, w1.x, acc[i][0]);
                acc[i][0] = fmaf(xv.z, w2.x, acc[i][0]); acc[i][0] = fmaf(xv.w, w3.x, acc[i][0]);
                acc[i][1] = fmaf(xv.x, w0.y, acc[i][1]); acc[i][1] = fmaf(xv.y, w1.y, acc[i][1]);
                acc[i][1] = fmaf(xv.z, w2.y, acc[i][1]); acc[i][1] = fmaf(xv.w, w3.y, acc[i][1]);
                acc[i][2] = fmaf(xv.x, w0.z, acc[i][2]); acc[i][2] = fmaf(xv.y, w1.z, acc[i][2]);
                acc[i][2] = fmaf(xv.z, w2.z, acc[i][2]); acc[i][2] = fmaf(xv.w, w3.z, acc[i][2]);
                acc[i][3] = fmaf(xv.x, w0.w, acc[i][3]); acc[i][3] = fmaf(xv.y, w1.w, acc[i][3]);
                acc[i][3] = fmaf(xv.z, w2.w, acc[i][3]); acc[i][3] = fmaf(xv.w, w3.w, acc[i][3]);
            }
        }
    }

    const float* bias = isG ? gb : cb;
    float b0v = bias[c4], b1v = bias[c4 + 1], b2v = bias[c4 + 2], b3v = bias[c4 + 3];
    #pragma unroll
    for (int i = 0; i < 8; ++i) {
        int m = m0 + rg * 8 + i;
        uint2 v;
        v.x = pack2h(acc[i][0] + b0v, acc[i][1] + b1v);
        v.y = pack2h(acc[i][2] + b2v, acc[i][3] + b3v);
        if (isG) *(uint2*)&pg[(size_t)m * 256 + (c4 >> 1)] = v;
        else     *(uint2*)&pc[(size_t)m * 256 + c4]        = v;
    }
}

// ============================================================================
// Recurrent kernel v2: REGISTER-RESIDENT f16 weights (384 KB/CU = 75% of RF).
// 256 blocks x 512 threads (8 waves, 2/SIMD @ <=256 VGPR), 2 batch rows/block.
// Thread (kh = tid&1, cA = tid>>1): gate cols {cA, cA+256} + cand col cA,
// K-window = halves [kh*128, kh*128+128). h/rh in LDS f16, read as uint4
// 2-way broadcasts (free). shfl_xor(1) merges K-halves. 2 barriers/step.
// Zero per-step weight memory traffic.
// ============================================================================
__global__ __launch_bounds__(512, 2) void gru_rec2(
    const int*   __restrict__ slen,
    const float* __restrict__ gk, const float* __restrict__ ck,
    const u32* pg,                 // aliases d_out (gate x-proj, f16 pairs)
    const u16* __restrict__ pc,    // ws (cand x-proj, f16)
    float* out)                    // aliases pg (barrier-ordered read-then-write)
{
    __shared__ _Float16 hs_h[2][256];
    __shared__ _Float16 rh_h[2][256];
    __shared__ float    uu[2][256];

    const int tid = threadIdx.x;
    const int b0  = blockIdx.x * 2;
    const int kh  = tid & 1;       // K-half (paired lanes)
    const int cA  = tid >> 1;      // reset col / cand col (0..255)
    const int cB  = cA + 256;      // update col

    // ---- one-time: recurrent weights into registers (f16 pairs along K) ----
    h2 wgA[64], wgB[64], wc[64];
    #pragma unroll
    for (int j = 0; j < 64; ++j) {
        const int k = 256 + kh * 128 + 2 * j;   // h-part rows of gk/ck
        h2 a, b, c;
        a.x = (_Float16)gk[(size_t)k * 512 + cA];
        a.y = (_Float16)gk[(size_t)(k + 1) * 512 + cA];
        b.x = (_Float16)gk[(size_t)k * 512 + cB];
        b.y = (_Float16)gk[(size_t)(k + 1) * 512 + cB];
        c.x = (_Float16)ck[(size_t)k * 256 + cA];
        c.y = (_Float16)ck[(size_t)(k + 1) * 256 + cA];
        wgA[j] = a; wgB[j] = b; wc[j] = c;
    }

    hs_h[tid >> 8][tid & 255] = (_Float16)0.0f;

    const int lenR = slen[b0 + kh];            // row handled at cand finalize
    const int colf = kh ? cB : cA;             // gate col this lane finalizes
    const int pgj  = colf >> 1;
    const int sel  = colf & 1;
    const u32* pg0 = pg + (size_t)(b0 + 0) * T_ * 256 + pgj;
    const u32* pg1 = pg + (size_t)(b0 + 1) * T_ * 256 + pgj;
    const u16* pcp = pc + (size_t)(b0 + kh) * T_ * 256 + cA;
    float*    outp = out + (size_t)(b0 + kh) * T_ * 256 + cA;

    const uint4* h4 = (const uint4*)&hs_h[0][0];  // row stride: 32 uint4
    const uint4* r4 = (const uint4*)&rh_h[0][0];

    for (int t = 0; t < T_; ++t) {
        // prefetch this step's projections (consumed after the barrier)
        const u32 pgv0 = __builtin_nontemporal_load(&pg0[(size_t)t * 256]);
        const u32 pgv1 = __builtin_nontemporal_load(&pg1[(size_t)t * 256]);
        const u16 pcv  = __builtin_nontemporal_load(&pcp[(size_t)t * 256]);

        __syncthreads();                       // A: h(t-1) writes visible

        // ---------------- gates ----------------
        float aA0 = 0.f, aA1 = 0.f, aB0 = 0.f, aB1 = 0.f;
        #pragma unroll
        for (int q = 0; q < 16; ++q) {
            U4H h0, h1;
            h0.u = h4[kh * 16 + q];            // row 0, K-window slice
            h1.u = h4[32 + kh * 16 + q];       // row 1
            #pragma unroll
            for (int j = 0; j < 4; ++j) {
                h2 w0 = wgA[4 * q + j], w1 = wgB[4 * q + j];
                aA0 = FDOT2(h0.p[j], w0, aA0);
                aA1 = FDOT2(h1.p[j], w0, aA1);
                aB0 = FDOT2(h0.p[j], w1, aB0);
                aB1 = FDOT2(h1.p[j], w1, aB1);
            }
        }
        aA0 += __shfl_xor(aA0, 1); aA1 += __shfl_xor(aA1, 1);
        aB0 += __shfl_xor(aB0, 1); aB1 += __shfl_xor(aB1, 1);

        const float pr0 = unp(pgv0, sel), pr1 = unp(pgv1, sel);
        if (kh == 0) {   // finalize reset gate for col cA -> stage r*h
            float g0 = sigmoid_f(aA0 + pr0);
            float g1 = sigmoid_f(aA1 + pr1);
            rh_h[0][cA] = (_Float16)(g0 * (float)hs_h[0][cA]);
            rh_h[1][cA] = (_Float16)(g1 * (float)hs_h[1][cA]);
        } else {         // finalize update gate for col cA
            uu[0][cA] = sigmoid_f(aB0 + pr0);
            uu[1][cA] = sigmoid_f(aB1 + pr1);
        }
        __syncthreads();                       // B: rh/uu ready

        // ---------------- candidate ----------------
        float c0 = 0.f, c1 = 0.f;
        #pragma unroll
        for (int q = 0; q < 16; ++q) {
            U4H r0, r1;
            r0.u = r4[kh * 16 + q];
            r1.u = r4[32 + kh * 16 + q];
            #pragma unroll
            for (int j = 0; j < 4; ++j) {
                h2 w = wc[4 * q + j];
                c0 = FDOT2(r0.p[j], w, c0);
                c1 = FDOT2(r1.p[j], w, c1);
            }
        }
        c0 += __shfl_xor(c0, 1); c1 += __shfl_xor(c1, 1);

        {   // lane kh finalizes batch row kh, column cA
            float csum = kh ? c1 : c0;
            float cd   = tanh_f(csum + (float)*(const _Float16*)&pcv);
            float u    = uu[kh][cA];
            float hold = (float)hs_h[kh][cA];
            float hn   = u * hold + (1.0f - u) * cd;
            bool  valid = (t < lenR);
            __builtin_nontemporal_store(valid ? hn : 0.0f, &outp[(size_t)t * 256]);
            if (valid) hs_h[kh][cA] = (_Float16)hn;
        }
    }
}

extern "C" void kernel_launch(void* const* d_in, const int* in_sizes, int n_in,
                              void* d_out, int out_size, void* d_ws, size_t ws_size,
                              hipStream_t stream) {
    const float* x    = (const float*)d_in[0];
    const int*   slen = (const int*)  d_in[1];
    const float* gk   = (const float*)d_in[2];
    const float* gb   = (const float*)d_in[3];
    const float* ck   = (const float*)d_in[4];
    const float* cb   = (const float*)d_in[5];
    float* out = (float*)d_out;
    u32*   pg  = (u32*)d_out;
    u16*   pc  = (u16*)d_ws;   // 52.4 MB cand x-proj (ws verified >= this in R2/R3)

    dim3 pgrid(1600, 6);
    proj_x<<<pgrid, 256, 0, stream>>>(x, gk, gb, ck, cb, pg, pc);
    gru_rec2<<<256, 512, 0, stream>>>(slen, gk, ck, pg, pc, out);
}